// Round 6
// baseline (721.556 us; speedup 1.0000x reference)
//
#include <hip/hip_runtime.h>
#include <hip/hip_fp16.h>
#include <stdint.h>

#define IN_F   4096
#define OUT_F  11008
#define TOKENS 2048
#define BM 128
#define BN 128
#define BK 64
#define NT (IN_F / BK)     // 64 K-tiles
#define NGROUP 32
#define OPW (OUT_F / 8)    // packed-zero words per group row

typedef _Float16 f16;
typedef __attribute__((ext_vector_type(2))) _Float16 f16x2;
typedef __attribute__((ext_vector_type(8))) _Float16 f16x8;
typedef __attribute__((ext_vector_type(16))) float f32x16;

typedef __attribute__((address_space(3))) uint32_t lds_u32_t;
typedef const __attribute__((address_space(1))) uint32_t glb_u32_t;

#define SB0() __builtin_amdgcn_sched_barrier(0)

static __device__ __forceinline__ void gload_lds16(const void* g, void* l) {
    __builtin_amdgcn_global_load_lds((glb_u32_t*)g, (lds_u32_t*)l, 16, 0, 0);
}

// dequant one packed word -> 8 f16 in pair-permuted k-order (j, j+4)
static __device__ __forceinline__ f16x8 dequant8(uint32_t w, f16x2 sv, f16x2 zv) {
    uint32_t p0 = (w & 0x000F000Fu) | 0x64006400u;           // 1024 + nibble (exact f16)
    uint32_t p1 = ((w >> 4)  & 0x000F000Fu) | 0x64006400u;
    uint32_t p2 = ((w >> 8)  & 0x000F000Fu) | 0x64006400u;
    uint32_t p3 = ((w >> 12) & 0x000F000Fu) | 0x64006400u;
    f16x2 h0 = (__builtin_bit_cast(f16x2, p0) + zv) * sv;    // exact (w - z - 1), then * s
    f16x2 h1 = (__builtin_bit_cast(f16x2, p1) + zv) * sv;
    f16x2 h2 = (__builtin_bit_cast(f16x2, p2) + zv) * sv;
    f16x2 h3 = (__builtin_bit_cast(f16x2, p3) + zv) * sv;
    f16x8 o;
    o[0] = h0[0]; o[1] = h0[1];
    o[2] = h1[0]; o[3] = h1[1];
    o[4] = h2[0]; o[5] = h2[1];
    o[6] = h3[0]; o[7] = h3[1];
    return o;
}

// pre-pass: x f32 -> f16 with intra-octet pair permutation (0,4,1,5,2,6,3,7)
__global__ __launch_bounds__(256) void cvt_perm_kernel(const float* __restrict__ x,
                                                       f16* __restrict__ xws) {
    const int o = blockIdx.x * 256 + threadIdx.x;   // octet id
    const float4 a = *reinterpret_cast<const float4*>(x + (size_t)o * 8);
    const float4 b = *reinterpret_cast<const float4*>(x + (size_t)o * 8 + 4);
    f16x8 v;
    v[0] = (f16)a.x; v[1] = (f16)b.x; v[2] = (f16)a.y; v[3] = (f16)b.y;
    v[4] = (f16)a.z; v[5] = (f16)b.z; v[6] = (f16)a.w; v[7] = (f16)b.w;
    *reinterpret_cast<f16x8*>(xws + (size_t)o * 8) = v;
}

// build per-lane (2-column) group constants from prefetched scale/zero words
#define MKC2() {                                                        \
    _Pragma("unroll") for (int f = 0; f < 2; ++f) {                     \
        const float sf_ = (float)swp[f] * ssv[f] - qzs[f];              \
        const int z_ = (int)((zwp[f] >> ((cf[f] & 7) * 4)) & 0xFu);     \
        const f16 sh_ = (f16)sf_;                                       \
        const f16 zh_ = (f16)(float)(-(1025 + z_));                     \
        sv[f][0] = sh_; sv[f][1] = sh_;                                 \
        zv[f][0] = zh_; zv[f][1] = zh_;                                 \
    }                                                                   \
}

// One K-tile: compute from Abuf[C] + words W; stage A(T+1) -> Abuf[C^1];
// prefetch words(T+1) -> NW; single counted vmcnt + single barrier.
#define TILE(C, T, W, NW, EVEN)                                                   \
  {                                                                               \
    const int tn_ = ((T) + 1 < NT) ? (T) + 1 : NT - 1;                            \
    if (EVEN) {  /* prefetch next group's scale/zero words (4 dwords) */          \
      const int gp_ = ((T) >> 1) + 1 < NGROUP ? ((T) >> 1) + 1 : NGROUP - 1;      \
      _Pragma("unroll") for (int f = 0; f < 2; ++f) {                             \
        swp[f] = qscales[(size_t)gp_ * OUT_F + cf[f]];                            \
        zwp[f] = qzeros[(size_t)gp_ * OPW + (cf[f] >> 3)];                        \
      }                                                                           \
    }                                                                             \
    SB0();                                                                        \
    if constexpr (USE_WS) {  /* 4 A-gloads for tile T+1 */                        \
      _Pragma("unroll") for (int i = 0; i < 4; ++i)                               \
        gload_lds16(asrc0 + (size_t)tn_ * BK + (size_t)i * (32 * IN_F),           \
                    &Abuf[(C) ^ 1][i * 2048 + tid * 8]);                          \
    }                                                                             \
    SB0();  /* pin: [sz][gloads][B-words] issue order for the vmcnt count */      \
    _Pragma("unroll") for (int kk = 0; kk < 4; ++kk)                              \
      _Pragma("unroll") for (int f = 0; f < 2; ++f)                               \
        NW[kk * 2 + f] =                                                          \
            qweight[(size_t)(tn_ * 8 + kk * 2 + hl) * OUT_F + cf[f]];             \
    SB0();                                                                        \
    if constexpr (!USE_WS) { stage_A_f((C) ^ 1, tn_); }                           \
    _Pragma("unroll") for (int kk = 0; kk < 4; ++kk) {                            \
      f16x8 af0 = *reinterpret_cast<const f16x8*>(&Abuf[C][arow0 + koff[kk]]);    \
      f16x8 af1 = *reinterpret_cast<const f16x8*>(&Abuf[C][arow0 + 2048 + koff[kk]]);\
      f16x8 bf0 = dequant8(W[kk * 2 + 0], sv[0], zv[0]);                          \
      f16x8 bf1 = dequant8(W[kk * 2 + 1], sv[1], zv[1]);                          \
      __builtin_amdgcn_s_setprio(1);                                              \
      acc00 = __builtin_amdgcn_mfma_f32_32x32x16_f16(af0, bf0, acc00, 0, 0, 0);   \
      acc01 = __builtin_amdgcn_mfma_f32_32x32x16_f16(af0, bf1, acc01, 0, 0, 0);   \
      acc10 = __builtin_amdgcn_mfma_f32_32x32x16_f16(af1, bf0, acc10, 0, 0, 0);   \
      acc11 = __builtin_amdgcn_mfma_f32_32x32x16_f16(af1, bf1, acc11, 0, 0, 0);   \
      __builtin_amdgcn_s_setprio(0);                                              \
    }                                                                             \
    if (!(EVEN)) { MKC2(); }  /* build consts for next group */                   \
    if constexpr (USE_WS) {                                                       \
      /* retire the 4 A-gloads (oldest); leave the 8 B-dwords in flight */        \
      asm volatile("s_waitcnt vmcnt(8)" ::: "memory");                            \
    } else {                                                                      \
      asm volatile("s_waitcnt lgkmcnt(0)" ::: "memory");                          \
    }                                                                             \
    __builtin_amdgcn_s_barrier();                                                 \
  }

template<bool USE_WS>
__global__ __launch_bounds__(256, 4) void qgemm_kernel(
    const float*    __restrict__ x,
    const f16*      __restrict__ xws,
    const uint32_t* __restrict__ qweight,
    const uint32_t* __restrict__ qzeros,
    const int*      __restrict__ qscales,
    const float*    __restrict__ qscales_zeros,
    const float*    __restrict__ qscales_scales,
    float*          __restrict__ out)
{
    // A only in LDS: [128 rows][8 chunks]; chunk (row, slot) holds octet slot^(row&7)
    __shared__ __align__(16) f16 Abuf[2][BM * BK];   // 2 x 16 KiB

    const int tid  = threadIdx.x;
    const int lane = tid & 63;
    const int wid  = tid >> 6;      // 0..3
    const int wm   = wid >> 1;      // 0..1 (M half)
    const int wn   = wid & 1;       // 0..1 (N half)
    const int l31  = lane & 31, hl = lane >> 5, l7 = lane & 7;

    // XCD locality: mt = blk&15 -> XCD (blk&7) hosts mt {x, x+8} A-panels in L2
    const int mt = blockIdx.x & 15;
    const int nt = blockIdx.x >> 4;
    const int m0 = mt * BM;
    const int n0 = nt * BN;

    // ---------- B side: per-lane 2 columns, fragment == one packed word ----------
    int cf[2];
    cf[0] = n0 + wn * 64 + l31;
    cf[1] = cf[0] + 32;
    float ssv[2], qzs[2];
    #pragma unroll
    for (int f = 0; f < 2; ++f) {
        ssv[f] = qscales_scales[cf[f]];
        qzs[f] = qscales_zeros[cf[f]] * ssv[f];
    }

    // ---------- A staging: 4 chunks/thread, linear dest, swizzled source ----------
    const int trow = tid >> 3;                   // 0..31
    const int oct  = (tid & 7) ^ (trow & 7);     // invariant across the 4 chunks
    const f16*   asrc0 = xws + (size_t)(m0 + trow) * IN_F + oct * 8;
    const float* fsrc0 = x   + (size_t)(m0 + trow) * IN_F + oct * 8;

    // ---------- A fragment read offsets (f16 units) ----------
    const int arow0 = (wm * 64 + l31) * BK;
    int koff[4];
    #pragma unroll
    for (int kk = 0; kk < 4; ++kk) koff[kk] = ((kk * 2 + hl) ^ l7) * 8;

    f32x16 acc00, acc01, acc10, acc11;
    #pragma unroll
    for (int r = 0; r < 16; ++r) { acc00[r] = 0.f; acc01[r] = 0.f; acc10[r] = 0.f; acc11[r] = 0.f; }

    auto stage_A_f = [&](int bufi, int tt) {
        #pragma unroll
        for (int i = 0; i < 4; ++i) {
            const float* p = fsrc0 + (size_t)tt * BK + (size_t)i * (32 * IN_F);
            const float4 v0 = *reinterpret_cast<const float4*>(p);
            const float4 v1 = *reinterpret_cast<const float4*>(p + 4);
            f16x8 v;
            v[0] = (f16)v0.x; v[1] = (f16)v1.x; v[2] = (f16)v0.y; v[3] = (f16)v1.y;
            v[4] = (f16)v0.z; v[5] = (f16)v1.z; v[6] = (f16)v0.w; v[7] = (f16)v1.w;
            *reinterpret_cast<f16x8*>(&Abuf[bufi][i * 2048 + tid * 8]) = v;
        }
    };

    uint32_t w0[8], w1[8];
    int swp[2]; uint32_t zwp[2];
    f16x2 sv[2], zv[2];

    // ---------------- prologue ----------------
    {
        #pragma unroll
        for (int kk = 0; kk < 4; ++kk)
            #pragma unroll
            for (int f = 0; f < 2; ++f)
                w0[kk * 2 + f] = qweight[(size_t)(kk * 2 + hl) * OUT_F + cf[f]];
        #pragma unroll
        for (int f = 0; f < 2; ++f) {       // group 0 words
            swp[f] = qscales[cf[f]];
            zwp[f] = qzeros[cf[f] >> 3];
        }
        MKC2();                             // consts for group 0 (tiles 0,1)
        #pragma unroll
        for (int f = 0; f < 2; ++f) {       // group 1 prefetch
            swp[f] = qscales[OUT_F + cf[f]];
            zwp[f] = qzeros[OPW + (cf[f] >> 3)];
        }
        if constexpr (USE_WS) {
            #pragma unroll
            for (int i = 0; i < 4; ++i)
                gload_lds16(asrc0 + (size_t)i * (32 * IN_F),
                            &Abuf[0][i * 2048 + tid * 8]);
        } else {
            stage_A_f(0, 0);
        }
        asm volatile("s_waitcnt vmcnt(0)" ::: "memory");
        asm volatile("s_waitcnt lgkmcnt(0)" ::: "memory");
        __builtin_amdgcn_s_barrier();
    }

    // ---------------- main loop: 2 tiles / iter (compile-time buf + word parity) ----
    for (int t = 0; t < NT; t += 2) {
        TILE(0, t,     w0, w1, 1)
        TILE(1, t + 1, w1, w0, 0)
    }

    // ---------------- epilogue: 32x32 C/D: col=lane&31, row=(r&3)+8*(r>>2)+4*hl ----
    const int ocol0 = n0 + wn * 64 + l31;
    const int orow0 = m0 + wm * 64 + 4 * hl;
    #pragma unroll
    for (int r = 0; r < 16; ++r) {
        const int rr = orow0 + (r & 3) + 8 * (r >> 2);
        out[(size_t)rr * OUT_F + ocol0]           = acc00[r];
        out[(size_t)rr * OUT_F + ocol0 + 32]      = acc01[r];
        out[(size_t)(rr + 32) * OUT_F + ocol0]      = acc10[r];
        out[(size_t)(rr + 32) * OUT_F + ocol0 + 32] = acc11[r];
    }
}

extern "C" void kernel_launch(void* const* d_in, const int* in_sizes, int n_in,
                              void* d_out, int out_size, void* d_ws, size_t ws_size,
                              hipStream_t stream) {
    const float*    xp  = (const float*)d_in[0];
    const uint32_t* qw  = (const uint32_t*)d_in[1];
    const uint32_t* qz  = (const uint32_t*)d_in[2];
    const int*      qs  = (const int*)d_in[3];
    const float*    qsz = (const float*)d_in[4];
    const float*    qss = (const float*)d_in[5];
    // d_in[6] = g_idx: identity grouping (k/128), folded into the kernel.
    float* outp = (float*)d_out;

    const int grid = (TOKENS / BM) * (OUT_F / BN);   // 16 * 86 = 1376
    const size_t need = (size_t)TOKENS * IN_F * sizeof(f16);   // 16 MiB

    if (ws_size >= need) {
        f16* xws = (f16*)d_ws;
        cvt_perm_kernel<<<(TOKENS * IN_F / 8) / 256, 256, 0, stream>>>(xp, xws);
        qgemm_kernel<true><<<grid, 256, 0, stream>>>(xp, xws, qw, qz, qs, qsz, qss, outp);
    } else {
        qgemm_kernel<false><<<grid, 256, 0, stream>>>(xp, (const f16*)nullptr,
                                                      qw, qz, qs, qsz, qss, outp);
    }
}

// Round 7
// 396.583 us; speedup vs baseline: 1.8194x; 1.8194x over previous
//
#include <hip/hip_runtime.h>
#include <hip/hip_fp16.h>
#include <stdint.h>

#define IN_F   4096
#define OUT_F  11008
#define TOKENS 2048
#define BM 256
#define BN 256
#define BK 64
#define NT (IN_F / BK)     // 64 K-tiles
#define NGROUP 32
#define OPW (OUT_F / 8)

typedef _Float16 f16;
typedef __attribute__((ext_vector_type(2))) _Float16 f16x2;
typedef __attribute__((ext_vector_type(8))) _Float16 f16x8;
typedef __attribute__((ext_vector_type(4))) float f32x4;

typedef __attribute__((address_space(3))) uint32_t lds_u32_t;
typedef const __attribute__((address_space(1))) uint32_t glb_u32_t;

#define SB0() __builtin_amdgcn_sched_barrier(0)

static __device__ __forceinline__ void gload_lds16(const void* g, void* l) {
    __builtin_amdgcn_global_load_lds((glb_u32_t*)g, (lds_u32_t*)l, 16, 0, 0);
}

// dequant one packed word -> 8 f16 in pair-permuted k-order (j, j+4)
static __device__ __forceinline__ f16x8 dequant8(uint32_t w, f16x2 sv, f16x2 zv) {
    uint32_t p0 = (w & 0x000F000Fu) | 0x64006400u;           // 1024 + nibble (exact f16)
    uint32_t p1 = ((w >> 4)  & 0x000F000Fu) | 0x64006400u;
    uint32_t p2 = ((w >> 8)  & 0x000F000Fu) | 0x64006400u;
    uint32_t p3 = ((w >> 12) & 0x000F000Fu) | 0x64006400u;
    f16x2 h0 = (__builtin_bit_cast(f16x2, p0) + zv) * sv;    // exact (w - z - 1), then * s
    f16x2 h1 = (__builtin_bit_cast(f16x2, p1) + zv) * sv;
    f16x2 h2 = (__builtin_bit_cast(f16x2, p2) + zv) * sv;
    f16x2 h3 = (__builtin_bit_cast(f16x2, p3) + zv) * sv;
    f16x8 o;
    o[0] = h0[0]; o[1] = h0[1];
    o[2] = h1[0]; o[3] = h1[1];
    o[4] = h2[0]; o[5] = h2[1];
    o[6] = h3[0]; o[7] = h3[1];
    return o;
}

// pre-pass: x f32 -> f16 with intra-octet pair permutation (0,4,1,5,2,6,3,7)
__global__ __launch_bounds__(256) void cvt_perm_kernel(const float* __restrict__ x,
                                                       f16* __restrict__ xws) {
    const int o = blockIdx.x * 256 + threadIdx.x;   // octet id
    const float4 a = *reinterpret_cast<const float4*>(x + (size_t)o * 8);
    const float4 b = *reinterpret_cast<const float4*>(x + (size_t)o * 8 + 4);
    f16x8 v;
    v[0] = (f16)a.x; v[1] = (f16)b.x; v[2] = (f16)a.y; v[3] = (f16)b.y;
    v[4] = (f16)a.z; v[5] = (f16)b.z; v[6] = (f16)a.w; v[7] = (f16)b.w;
    *reinterpret_cast<f16x8*>(xws + (size_t)o * 8) = v;
}

template<bool USE_WS>
__global__ __launch_bounds__(512, 1) void qgemm_kernel(
    const float*    __restrict__ x,
    const f16*      __restrict__ xws,
    const uint32_t* __restrict__ qweight,
    const uint32_t* __restrict__ qzeros,
    const int*      __restrict__ qscales,
    const float*    __restrict__ qscales_zeros,
    const float*    __restrict__ qscales_scales,
    float*          __restrict__ out)
{
    // chunk (row, slot) holds k-octet (slot ^ (row&7)) — conflict-free per 8-lane phase
    __shared__ __align__(16) f16 Abuf[2][BM * BK];   // 2 x 32 KiB
    __shared__ __align__(16) f16 Bbuf[2][BN * BK];   // 2 x 32 KiB

    const int tid  = threadIdx.x;
    const int lane = tid & 63;
    const int wid  = tid >> 6;      // 0..7
    const int wm   = wid >> 2;      // 0..1 (M half: 128 rows)
    const int wn   = wid & 3;       // 0..3 (N quarter: 64 cols)

    // M-tiles == 8 == NXCD: each XCD keeps exactly one 256-row A-panel in its L2
    const int mt = blockIdx.x & 7;
    const int nt = blockIdx.x >> 3;
    const int m0 = mt * BM;
    const int n0 = nt * BN;

    // ---------- B side: thread owns 1 column, 4 consecutive k-octet rows ----------
    const int colb = tid & 255;
    const int rg4  = (tid >> 8) << 2;    // 0 or 4
    const int ncol = n0 + colb;
    const float ssv   = qscales_scales[ncol];
    const float qzssv = qscales_zeros[ncol] * ssv;
    int bo[4];
    #pragma unroll
    for (int r = 0; r < 4; ++r)
        bo[r] = colb * BK + ((rg4 + r) ^ (colb & 7)) * 8;
    const uint32_t* bptr = qweight + (size_t)rg4 * OUT_F + ncol;

    // ---------- A side: 4 chunks/thread, linear LDS dest, swizzled source ----------
    const f16*   asrc[4];
    const float* fsrc[4];
    int aoff[4];
    #pragma unroll
    for (int i = 0; i < 4; ++i) {
        const int cid = i * 512 + tid;
        const int row = cid >> 3, slot = cid & 7;
        const int oct = slot ^ (row & 7);
        asrc[i] = xws + (size_t)(m0 + row) * IN_F + oct * 8;
        fsrc[i] = x   + (size_t)(m0 + row) * IN_F + oct * 8;
        aoff[i] = cid * 8;               // f16 elems (16B chunks)
    }

    // ---------- fragment read offsets ----------
    const int lr = lane & 15;
    const int lo = lane >> 4;            // k-octet within 32-k step
    int offA[2][8], offB[2][4];
    #pragma unroll
    for (int k2 = 0; k2 < 2; ++k2) {
        #pragma unroll
        for (int f = 0; f < 8; ++f) {
            const int ra = wm * 128 + f * 16 + lr;
            offA[k2][f] = ra * BK + ((k2 * 4 + lo) ^ (ra & 7)) * 8;
        }
        #pragma unroll
        for (int f = 0; f < 4; ++f) {
            const int rb = wn * 64 + f * 16 + lr;
            offB[k2][f] = rb * BK + ((k2 * 4 + lo) ^ (rb & 7)) * 8;
        }
    }

    f32x4 acc[8][4];
    #pragma unroll
    for (int i = 0; i < 8; ++i)
        #pragma unroll
        for (int j = 0; j < 4; ++j) {
            f32x4 z = {0.f, 0.f, 0.f, 0.f};
            acc[i][j] = z;
        }

    auto load_bw = [&](int t_, uint32_t* w) {
        const uint32_t* p = bptr + (size_t)t_ * 8 * OUT_F;
        #pragma unroll
        for (int r = 0; r < 4; ++r)
            w[r] = p[(size_t)r * OUT_F];
    };
    auto mkc = [&](f16x2& sv_, f16x2& zv_, int sw_, uint32_t zw_) {
        const float sf = (float)sw_ * ssv - qzssv;
        const int   z  = (int)((zw_ >> ((ncol & 7) * 4)) & 0xFu);
        const f16 sh = (f16)sf;
        const f16 zh = (f16)(float)(-(1025 + z));   // -(1024 + (z+1)), exact in f16
        sv_[0] = sh; sv_[1] = sh;
        zv_[0] = zh; zv_[1] = zh;
    };
    auto stage_B = [&](int buf, const uint32_t* w, f16x2 sv_, f16x2 zv_) {
        #pragma unroll
        for (int r = 0; r < 4; ++r)
            *reinterpret_cast<f16x8*>(&Bbuf[buf][bo[r]]) = dequant8(w[r], sv_, zv_);
    };
    auto stage_A_g = [&](int buf, int t_) {
        #pragma unroll
        for (int i = 0; i < 4; ++i)
            gload_lds16(asrc[i] + (size_t)t_ * BK, &Abuf[buf][aoff[i]]);
    };
    auto stage_A_f = [&](int buf, int t_) {
        #pragma unroll
        for (int i = 0; i < 4; ++i) {
            const float* p = fsrc[i] + (size_t)t_ * BK;
            const float4 v0 = *reinterpret_cast<const float4*>(p);
            const float4 v1 = *reinterpret_cast<const float4*>(p + 4);
            f16x8 v;
            v[0] = (f16)v0.x; v[1] = (f16)v1.x; v[2] = (f16)v0.y; v[3] = (f16)v1.y;
            v[4] = (f16)v0.z; v[5] = (f16)v1.z; v[6] = (f16)v0.w; v[7] = (f16)v1.w;
            *reinterpret_cast<f16x8*>(&Abuf[buf][aoff[i]]) = v;
        }
    };
    auto compute = [&](int buf) {
        #pragma unroll
        for (int k2 = 0; k2 < 2; ++k2) {
            f16x8 af[8], bf[4];
            #pragma unroll
            for (int f = 0; f < 8; ++f)
                af[f] = *reinterpret_cast<const f16x8*>(&Abuf[buf][offA[k2][f]]);
            #pragma unroll
            for (int f = 0; f < 4; ++f)
                bf[f] = *reinterpret_cast<const f16x8*>(&Bbuf[buf][offB[k2][f]]);
            __builtin_amdgcn_s_setprio(1);
            #pragma unroll
            for (int i = 0; i < 8; ++i)
                #pragma unroll
                for (int j = 0; j < 4; ++j)
                    acc[i][j] = __builtin_amdgcn_mfma_f32_16x16x32_f16(
                        af[i], bf[j], acc[i][j], 0, 0, 0);
            __builtin_amdgcn_s_setprio(0);
        }
    };

    uint32_t wcur[4], wnxt[4];
    int swN; uint32_t zwN;
    f16x2 sv, zv, svN, zvN;

    // ---------------- prologue: stage tile 0; prime tile-1 words + group-1 scales ----
    {
        uint32_t w0[4];
        load_bw(0, w0);
        const int      sw0 = qscales[ncol];
        const uint32_t zw0 = qzeros[ncol >> 3];
        if constexpr (USE_WS) stage_A_g(0, 0); else stage_A_f(0, 0);
        load_bw(1, wcur);
        swN = qscales[OUT_F + ncol];           // group 1
        zwN = qzeros[OPW + (ncol >> 3)];
        mkc(sv, zv, sw0, zw0);                 // group 0 (tiles 0,1)
        stage_B(0, w0, sv, zv);
        asm volatile("s_waitcnt vmcnt(0)" ::: "memory");
        asm volatile("s_waitcnt lgkmcnt(0)" ::: "memory");
        __builtin_amdgcn_s_barrier();
    }

    // ---------------- main loop: 2 tiles per iteration, 1 barrier per tile ----------
    for (int t = 0; t < NT; t += 2) {
        // ---- even body: compute tile t (buf0); stage tile t+1 (buf1)
        {
            mkc(svN, zvN, swN, zwN);                   // group t/2+1 (for odd body)
            stage_B(1, wcur, sv, zv);                  // tile t+1, group t/2
            if constexpr (USE_WS) stage_A_g(1, t + 1); else stage_A_f(1, t + 1);
            SB0();
            load_bw(t + 2 < NT ? t + 2 : NT - 1, wnxt);
            {
                const int g2 = (t >> 1) + 2 < NGROUP ? (t >> 1) + 2 : NGROUP - 1;
                swN = qscales[(size_t)g2 * OUT_F + ncol];
                zwN = qzeros[(size_t)g2 * OPW + (ncol >> 3)];
            }
            SB0();
            compute(0);
            if constexpr (USE_WS)
                asm volatile("s_waitcnt vmcnt(6)" ::: "memory");  // A(t+1) landed
            asm volatile("s_waitcnt lgkmcnt(0)" ::: "memory");
            __builtin_amdgcn_s_barrier();
        }
        // ---- odd body: compute tile t+1 (buf1); stage tile t+2 (buf0)
        {
            sv = svN; zv = zvN;                        // group t/2+1
            stage_B(0, wnxt, sv, zv);                  // tile t+2
            const int tn2 = t + 2 < NT ? t + 2 : NT - 1;
            if constexpr (USE_WS) stage_A_g(0, tn2); else stage_A_f(0, tn2);
            SB0();
            load_bw(t + 3 < NT ? t + 3 : NT - 1, wcur);
            SB0();
            compute(1);
            if constexpr (USE_WS)
                asm volatile("s_waitcnt vmcnt(4)" ::: "memory");  // A(t+2) landed
            asm volatile("s_waitcnt lgkmcnt(0)" ::: "memory");
            __builtin_amdgcn_s_barrier();
        }
    }

    // ---------------- epilogue: C/D layout col=lane&15, row=(lane>>4)*4+reg ----------
    const int orow = m0 + wm * 128 + lo * 4;
    const int ocol = n0 + wn * 64 + lr;
    #pragma unroll
    for (int i = 0; i < 8; ++i)
        #pragma unroll
        for (int j = 0; j < 4; ++j) {
            #pragma unroll
            for (int r = 0; r < 4; ++r)
                out[(size_t)(orow + i * 16 + r) * OUT_F + ocol + j * 16] = acc[i][j][r];
        }
}

extern "C" void kernel_launch(void* const* d_in, const int* in_sizes, int n_in,
                              void* d_out, int out_size, void* d_ws, size_t ws_size,
                              hipStream_t stream) {
    const float*    xp  = (const float*)d_in[0];
    const uint32_t* qw  = (const uint32_t*)d_in[1];
    const uint32_t* qz  = (const uint32_t*)d_in[2];
    const int*      qs  = (const int*)d_in[3];
    const float*    qsz = (const float*)d_in[4];
    const float*    qss = (const float*)d_in[5];
    // d_in[6] = g_idx: identity grouping (k/128), folded into the kernel.
    float* outp = (float*)d_out;

    const int grid = (TOKENS / BM) * (OUT_F / BN);   // 8 * 43 = 344
    const size_t need = (size_t)TOKENS * IN_F * sizeof(f16);   // 16 MiB

    if (ws_size >= need) {
        f16* xws = (f16*)d_ws;
        cvt_perm_kernel<<<(TOKENS * IN_F / 8) / 256, 256, 0, stream>>>(xp, xws);
        qgemm_kernel<true><<<grid, 512, 0, stream>>>(xp, xws, qw, qz, qs, qsz, qss, outp);
    } else {
        qgemm_kernel<false><<<grid, 512, 0, stream>>>(xp, (const f16*)nullptr,
                                                      qw, qz, qs, qsz, qss, outp);
    }
}

// Round 8
// 263.057 us; speedup vs baseline: 2.7430x; 1.5076x over previous
//
#include <hip/hip_runtime.h>
#include <hip/hip_fp16.h>
#include <stdint.h>

#define IN_F   4096
#define OUT_F  11008
#define TOKENS 2048
#define BM 128
#define BN 128
#define BK 64
#define NT (IN_F / BK)     // 64 K-tiles
#define NGROUP 32
#define OPW (OUT_F / 8)

typedef _Float16 f16;
typedef __attribute__((ext_vector_type(2))) _Float16 f16x2;
typedef __attribute__((ext_vector_type(8))) _Float16 f16x8;
typedef __attribute__((ext_vector_type(4))) float f32x4;

typedef __attribute__((address_space(3))) uint32_t lds_u32_t;
typedef const __attribute__((address_space(1))) uint32_t glb_u32_t;

#define SB0() __builtin_amdgcn_sched_barrier(0)

static __device__ __forceinline__ void gload_lds16(const void* g, void* l) {
    __builtin_amdgcn_global_load_lds((glb_u32_t*)g, (lds_u32_t*)l, 16, 0, 0);
}

// dequant one packed word -> 8 f16 in pair-permuted k-order (j, j+4)
static __device__ __forceinline__ f16x8 dequant8(uint32_t w, f16x2 sv, f16x2 zv) {
    uint32_t p0 = (w & 0x000F000Fu) | 0x64006400u;           // 1024 + nibble (exact f16)
    uint32_t p1 = ((w >> 4)  & 0x000F000Fu) | 0x64006400u;
    uint32_t p2 = ((w >> 8)  & 0x000F000Fu) | 0x64006400u;
    uint32_t p3 = ((w >> 12) & 0x000F000Fu) | 0x64006400u;
    f16x2 h0 = (__builtin_bit_cast(f16x2, p0) + zv) * sv;    // exact (w - z - 1), then * s
    f16x2 h1 = (__builtin_bit_cast(f16x2, p1) + zv) * sv;
    f16x2 h2 = (__builtin_bit_cast(f16x2, p2) + zv) * sv;
    f16x2 h3 = (__builtin_bit_cast(f16x2, p3) + zv) * sv;
    f16x8 o;
    o[0] = h0[0]; o[1] = h0[1];
    o[2] = h1[0]; o[3] = h1[1];
    o[4] = h2[0]; o[5] = h2[1];
    o[6] = h3[0]; o[7] = h3[1];
    return o;
}

// pre-pass: x f32 -> f16 with intra-octet pair permutation (0,4,1,5,2,6,3,7)
__global__ __launch_bounds__(256) void cvt_perm_kernel(const float* __restrict__ x,
                                                       f16* __restrict__ xws) {
    const int o = blockIdx.x * 256 + threadIdx.x;   // octet id
    const float4 a = *reinterpret_cast<const float4*>(x + (size_t)o * 8);
    const float4 b = *reinterpret_cast<const float4*>(x + (size_t)o * 8 + 4);
    f16x8 v;
    v[0] = (f16)a.x; v[1] = (f16)b.x; v[2] = (f16)a.y; v[3] = (f16)b.y;
    v[4] = (f16)a.z; v[5] = (f16)b.z; v[6] = (f16)a.w; v[7] = (f16)b.w;
    *reinterpret_cast<f16x8*>(xws + (size_t)o * 8) = v;
}

template<bool USE_WS>
__global__ __launch_bounds__(256, 4) void qgemm_kernel(
    const float*    __restrict__ x,
    const f16*      __restrict__ xws,
    const uint32_t* __restrict__ qweight,
    const uint32_t* __restrict__ qzeros,
    const int*      __restrict__ qscales,
    const float*    __restrict__ qscales_zeros,
    const float*    __restrict__ qscales_scales,
    float*          __restrict__ out)
{
    // chunk (row, slot) holds k-octet (slot ^ (row&7)) — conflict-free per 8-lane phase
    __shared__ __align__(16) f16 Abuf[2][BM * BK];   // 2 x 16 KiB
    __shared__ __align__(16) f16 Bbuf[2][BN * BK];   // 2 x 16 KiB  (total 64 KiB -> 2 blocks/CU)

    const int tid  = threadIdx.x;
    const int lane = tid & 63;
    const int wid  = tid >> 6;      // 0..3
    const int wm   = wid >> 1;      // 0..1 (M half: 64 rows)
    const int wn   = wid & 1;       // 0..1 (N half: 64 cols)

    // XCD map: bid&7 = XCD; mt = bid&15 -> XCD x hosts A-panels {x, x+8} (2 MB in L2)
    const int mt = blockIdx.x & 15;
    const int nt = blockIdx.x >> 4;
    const int m0 = mt * BM;
    const int n0 = nt * BN;

    // ---------- B side: thread owns 1 column, 4 consecutive k-octet rows ----------
    const int colb = tid & 127;
    const int rg4  = (tid >> 7) << 2;    // 0 or 4
    const int ncol = n0 + colb;
    const float ssv   = qscales_scales[ncol];
    const float qzssv = qscales_zeros[ncol] * ssv;
    int bo[4];
    #pragma unroll
    for (int r = 0; r < 4; ++r)
        bo[r] = colb * BK + ((rg4 + r) ^ (colb & 7)) * 8;
    const uint32_t* bptr = qweight + (size_t)rg4 * OUT_F + ncol;

    // ---------- A side: 4 chunks/thread, linear LDS dest, swizzled source ----------
    const f16*   asrc[4];
    const float* fsrc[4];
    int aoff[4];
    #pragma unroll
    for (int i = 0; i < 4; ++i) {
        const int cid = i * 256 + tid;           // 0..1023 chunks
        const int row = cid >> 3, slot = cid & 7;
        const int oct = slot ^ (row & 7);
        asrc[i] = xws + (size_t)(m0 + row) * IN_F + oct * 8;
        fsrc[i] = x   + (size_t)(m0 + row) * IN_F + oct * 8;
        aoff[i] = cid * 8;                       // f16 elems (16B chunks)
    }

    // ---------- fragment read offsets ----------
    const int lr = lane & 15;
    const int lo = lane >> 4;            // k-octet within 32-k step
    int offA[2][4], offB[2][4];
    #pragma unroll
    for (int k2 = 0; k2 < 2; ++k2) {
        #pragma unroll
        for (int f = 0; f < 4; ++f) {
            const int ra = wm * 64 + f * 16 + lr;
            offA[k2][f] = ra * BK + ((k2 * 4 + lo) ^ (ra & 7)) * 8;
            const int rb = wn * 64 + f * 16 + lr;
            offB[k2][f] = rb * BK + ((k2 * 4 + lo) ^ (rb & 7)) * 8;
        }
    }

    f32x4 acc[4][4];
    #pragma unroll
    for (int i = 0; i < 4; ++i)
        #pragma unroll
        for (int j = 0; j < 4; ++j) {
            f32x4 z = {0.f, 0.f, 0.f, 0.f};
            acc[i][j] = z;
        }

    auto load_bw = [&](int t_, uint32_t* w) {
        const uint32_t* p = bptr + (size_t)t_ * 8 * OUT_F;
        #pragma unroll
        for (int r = 0; r < 4; ++r)
            w[r] = p[(size_t)r * OUT_F];
    };
    auto mkc = [&](f16x2& sv_, f16x2& zv_, int sw_, uint32_t zw_) {
        const float sf = (float)sw_ * ssv - qzssv;
        const int   z  = (int)((zw_ >> ((ncol & 7) * 4)) & 0xFu);
        const f16 sh = (f16)sf;
        const f16 zh = (f16)(float)(-(1025 + z));   // -(1024 + (z+1)), exact in f16
        sv_[0] = sh; sv_[1] = sh;
        zv_[0] = zh; zv_[1] = zh;
    };
    auto stage_B = [&](int buf, const uint32_t* w, f16x2 sv_, f16x2 zv_) {
        #pragma unroll
        for (int r = 0; r < 4; ++r)
            *reinterpret_cast<f16x8*>(&Bbuf[buf][bo[r]]) = dequant8(w[r], sv_, zv_);
    };
    auto stage_A_g = [&](int buf, int t_) {
        #pragma unroll
        for (int i = 0; i < 4; ++i)
            gload_lds16(asrc[i] + (size_t)t_ * BK, &Abuf[buf][aoff[i]]);
    };
    auto stage_A_f = [&](int buf, int t_) {
        #pragma unroll
        for (int i = 0; i < 4; ++i) {
            const float* p = fsrc[i] + (size_t)t_ * BK;
            const float4 v0 = *reinterpret_cast<const float4*>(p);
            const float4 v1 = *reinterpret_cast<const float4*>(p + 4);
            f16x8 v;
            v[0] = (f16)v0.x; v[1] = (f16)v1.x; v[2] = (f16)v0.y; v[3] = (f16)v1.y;
            v[4] = (f16)v0.z; v[5] = (f16)v1.z; v[6] = (f16)v0.w; v[7] = (f16)v1.w;
            *reinterpret_cast<f16x8*>(&Abuf[buf][aoff[i]]) = v;
        }
    };
    auto compute = [&](int buf) {
        #pragma unroll
        for (int k2 = 0; k2 < 2; ++k2) {
            f16x8 af[4], bf[4];
            #pragma unroll
            for (int f = 0; f < 4; ++f)
                af[f] = *reinterpret_cast<const f16x8*>(&Abuf[buf][offA[k2][f]]);
            #pragma unroll
            for (int f = 0; f < 4; ++f)
                bf[f] = *reinterpret_cast<const f16x8*>(&Bbuf[buf][offB[k2][f]]);
            __builtin_amdgcn_s_setprio(1);
            #pragma unroll
            for (int i = 0; i < 4; ++i)
                #pragma unroll
                for (int j = 0; j < 4; ++j)
                    acc[i][j] = __builtin_amdgcn_mfma_f32_16x16x32_f16(
                        af[i], bf[j], acc[i][j], 0, 0, 0);
            __builtin_amdgcn_s_setprio(0);
        }
    };

    uint32_t wcur[4], wnxt[4];
    int swN; uint32_t zwN;
    f16x2 sv, zv, svN, zvN;

    // ---------------- prologue: stage tile 0; prime tile-1 words + group-1 scales ----
    {
        uint32_t w0[4];
        load_bw(0, w0);
        const int      sw0 = qscales[ncol];
        const uint32_t zw0 = qzeros[ncol >> 3];
        if constexpr (USE_WS) stage_A_g(0, 0); else stage_A_f(0, 0);
        load_bw(1, wcur);
        swN = qscales[OUT_F + ncol];           // group 1
        zwN = qzeros[OPW + (ncol >> 3)];
        mkc(sv, zv, sw0, zw0);                 // group 0 (tiles 0,1)
        stage_B(0, w0, sv, zv);
        asm volatile("s_waitcnt vmcnt(0)" ::: "memory");
        asm volatile("s_waitcnt lgkmcnt(0)" ::: "memory");
        __builtin_amdgcn_s_barrier();
    }

    // ---------------- main loop: 2 tiles per iteration, 1 barrier per tile ----------
    for (int t = 0; t < NT; t += 2) {
        // ---- even body: compute tile t (buf0); stage tile t+1 (buf1)
        {
            mkc(svN, zvN, swN, zwN);                   // group t/2+1 (for odd body)
            stage_B(1, wcur, sv, zv);                  // tile t+1, group t/2
            if constexpr (USE_WS) stage_A_g(1, t + 1); else stage_A_f(1, t + 1);
            SB0();
            load_bw(t + 2 < NT ? t + 2 : NT - 1, wnxt);
            {
                const int g2 = (t >> 1) + 2 < NGROUP ? (t >> 1) + 2 : NGROUP - 1;
                swN = qscales[(size_t)g2 * OUT_F + ncol];
                zwN = qzeros[(size_t)g2 * OPW + (ncol >> 3)];
            }
            SB0();
            compute(0);
            if constexpr (USE_WS)
                asm volatile("s_waitcnt vmcnt(6)" ::: "memory");  // A(t+1) landed
            asm volatile("s_waitcnt lgkmcnt(0)" ::: "memory");
            __builtin_amdgcn_s_barrier();
        }
        // ---- odd body: compute tile t+1 (buf1); stage tile t+2 (buf0)
        {
            sv = svN; zv = zvN;                        // group t/2+1
            stage_B(0, wnxt, sv, zv);                  // tile t+2
            const int tn2 = t + 2 < NT ? t + 2 : NT - 1;
            if constexpr (USE_WS) stage_A_g(0, tn2); else stage_A_f(0, tn2);
            SB0();
            load_bw(t + 3 < NT ? t + 3 : NT - 1, wcur);
            SB0();
            compute(1);
            if constexpr (USE_WS)
                asm volatile("s_waitcnt vmcnt(4)" ::: "memory");  // A(t+2) landed
            asm volatile("s_waitcnt lgkmcnt(0)" ::: "memory");
            __builtin_amdgcn_s_barrier();
        }
    }

    // ---------------- epilogue: C/D layout col=lane&15, row=(lane>>4)*4+reg ----------
    const int orow = m0 + wm * 64 + lo * 4;
    const int ocol = n0 + wn * 64 + lr;
    #pragma unroll
    for (int i = 0; i < 4; ++i)
        #pragma unroll
        for (int j = 0; j < 4; ++j) {
            #pragma unroll
            for (int r = 0; r < 4; ++r)
                out[(size_t)(orow + i * 16 + r) * OUT_F + ocol + j * 16] = acc[i][j][r];
        }
}

extern "C" void kernel_launch(void* const* d_in, const int* in_sizes, int n_in,
                              void* d_out, int out_size, void* d_ws, size_t ws_size,
                              hipStream_t stream) {
    const float*    xp  = (const float*)d_in[0];
    const uint32_t* qw  = (const uint32_t*)d_in[1];
    const uint32_t* qz  = (const uint32_t*)d_in[2];
    const int*      qs  = (const int*)d_in[3];
    const float*    qsz = (const float*)d_in[4];
    const float*    qss = (const float*)d_in[5];
    // d_in[6] = g_idx: identity grouping (k/128), folded into the kernel.
    float* outp = (float*)d_out;

    const int grid = (TOKENS / BM) * (OUT_F / BN);   // 16 * 86 = 1376
    const size_t need = (size_t)TOKENS * IN_F * sizeof(f16);   // 16 MiB

    if (ws_size >= need) {
        f16* xws = (f16*)d_ws;
        cvt_perm_kernel<<<(TOKENS * IN_F / 8) / 256, 256, 0, stream>>>(xp, xws);
        qgemm_kernel<true><<<grid, 256, 0, stream>>>(xp, xws, qw, qz, qs, qsz, qss, outp);
    } else {
        qgemm_kernel<false><<<grid, 256, 0, stream>>>(xp, (const f16*)nullptr,
                                                      qw, qz, qs, qsz, qss, outp);
    }
}